// Round 8
// baseline (85.542 us; speedup 1.0000x reference)
//
#include <hip/hip_runtime.h>
#include <math.h>
#include <float.h>

#define EPS 1e-6f
#define THRESHOLD 0.5f

#define NB 16
#define NPOLY 16
#define NVERT 200
#define NSEG_PER_POLY 199
#define NSEG_REAL (NPOLY * NSEG_PER_POLY)  // 3184 real segments per batch
#define NSEG_PAD 3200                      // padded to 64 slices * 50 segs
#define NPTB 300                           // points per batch (10 agents * 30)
#define NPOINTS 4800                       // 16 * 300
#define NSLICE 64
#define SEG_PER_SLICE 50                   // compile-time constant trip count

// 32-byte per-segment record. In seg_kernel the index is uniform
// (blockIdx + loop var) -> scalar s_load_dwordx8 through the constant cache,
// zero vector-memory ops in the hot loop. Each VALU op consumes at most one
// of these scalars (1-SGPR-per-vector-inst constraint satisfied).
struct __align__(32) Seg {
    float sx, sy, evx, evy, inv_esq, slope_eps, inv_slope, ey;
};

// ---------------------------------------------------------------------------
// Pass 1: per-(batch, padded-segment) precompute -> global table.
//   slope_eps = (ey-sy)/((ex-sx)+EPS)+EPS  -- identical rounding order to ref
//   inv_esq   = 1/(esq+EPS)                -- distance path only (ulp-tolerant)
//   inv_slope = v_rcp_f32(slope_eps)       -- crossing fast path only
// Pad entries (s >= 3184): dsq evaluates to +inf (never the min) and
// cond_y = (1e30<=py) XOR (1e30<=py) = false (never crosses, never falls back).
// Also zeroes out[] (poisoned 0xAA before every timed launch).
// ---------------------------------------------------------------------------
__global__ __launch_bounds__(256) void precompute_kernel(
    const float* __restrict__ polys,
    Seg* __restrict__ table,
    float* __restrict__ out)
{
    const int idx = blockIdx.x * 256 + threadIdx.x;   // 0..51199
    if (idx < 160) out[idx] = 0.0f;

    const int b = idx / NSEG_PAD;
    const int s = idx % NSEG_PAD;

    Seg e;
    if (s < NSEG_REAL) {
        const int m = s / NSEG_PER_POLY;
        const int v = s % NSEG_PER_POLY;
        const float2* poly = (const float2*)polys + ((size_t)(b * NPOLY + m) * NVERT);
        const float2 S = poly[v];
        const float2 E = poly[v + 1];
        e.sx = S.x; e.sy = S.y;
        e.evx = E.x - S.x;
        e.evy = E.y - S.y;
        const float esq = e.evx * e.evx + e.evy * e.evy;
        e.inv_esq   = 1.0f / (esq + EPS);
        e.slope_eps = e.evy / (e.evx + EPS) + EPS;    // exact IEEE, ref order
        e.inv_slope = __builtin_amdgcn_rcpf(e.slope_eps);
        e.ey = E.y;
    } else {
        e.sx = 1e30f; e.sy = 1e30f; e.evx = 0.0f; e.evy = 0.0f;
        e.inv_esq = 0.0f; e.slope_eps = 1.0f; e.inv_slope = 1.0f; e.ey = 1e30f;
    }
    table[idx] = e;
}

// ---------------------------------------------------------------------------
// Pass 2: one block per (batch, slice); lane = point. Segment operands arrive
// via scalar loads (SGPRs); constant trip count 50 lets the compiler unroll
// and batch s_loads far ahead of the VALU — no per-iteration LDS/VMEM wait.
// Crossing test: rcp fast path + per-lane EXACT-div fallback (bit-matches
// numpy ref; fallback ~never taken). Dual accumulators for fmin/add ILP.
// ---------------------------------------------------------------------------
__global__ __launch_bounds__(320) void seg_kernel(
    const float* __restrict__ points,
    const Seg* __restrict__ table,
    float2* __restrict__ part)        // [NSLICE][NPOINTS]
{
    const int slice = blockIdx.x;       // 0..63
    const int b     = blockIdx.y;       // 0..15
    const int lp    = threadIdx.x;      // 0..319; points 0..299 valid
    const bool active = lp < NPTB;

    const int pidx = b * NPTB + (active ? lp : 0);
    const float2 pt = *(const float2*)(points + (size_t)pidx * 2);
    const float px = pt.x, py = pt.y;

    const Seg* __restrict__ tb = table + (b * NSEG_PAD + slice * SEG_PER_SLICE);

    float min_a = FLT_MAX, min_b = FLT_MAX;
    int cr_a = 0, cr_b = 0;

    auto body = [&](int j, float& mn, int& cr) {
        const Seg sg = tb[j];               // uniform -> s_load_dwordx8

        // ---- point-to-segment squared distance (ulp-tolerant path) ----
        const float v1x = px - sg.sx;
        const float v1y = py - sg.sy;
        const float dot = fmaf(v1y, sg.evy, v1x * sg.evx);
        const float t   = __builtin_amdgcn_fmed3f(dot * sg.inv_esq, 0.0f, 1.0f);
        const float dx  = fmaf(-sg.evx, t, v1x);
        const float dy  = fmaf(-sg.evy, t, v1y);
        const float dsq = fmaf(dy, dy, dx * dx);
        mn = fminf(mn, dsq);

        // ---- even-odd crossing: rcp fast path + exact-div fallback ----
        const bool cond_y = (sg.sy <= py) != (sg.ey <= py);  // == ref, exact
        const float q    = v1y * sg.inv_slope;               // ~3 ulp
        const float ixa  = sg.sx + q;
        const float diff = ixa - px;
        const float err  = fmaf(fabsf(q) + fabsf(ixa), 1e-6f, 1e-30f);
        bool left = diff > 0.0f;
        if (cond_y && !(fabsf(diff) > err)) {
            // rare: decision within rcp noise — replicate ref bit-exactly
            left = (sg.sx + v1y / sg.slope_eps) > px;
        }
        cr += (cond_y && left) ? 1 : 0;
    };

    for (int j = 0; j < SEG_PER_SLICE; j += 2) {   // constant 25 trips
        body(j,     min_a, cr_a);
        body(j + 1, min_b, cr_b);
    }

    if (active) {
        part[slice * NPOINTS + pidx] =
            make_float2(fminf(min_a, min_b), __int_as_float(cr_a + cr_b));
    }
}

// ---------------------------------------------------------------------------
// Pass 3: per-point reduction over 64 slices + epilogue + atomic into out.
// ---------------------------------------------------------------------------
__global__ __launch_bounds__(256) void final_kernel(
    const float2* __restrict__ part,
    float* __restrict__ out)
{
    const int p = blockIdx.x * 256 + threadIdx.x;
    if (p >= NPOINTS) return;

    float md = FLT_MAX;
    int c = 0;
    #pragma unroll 8
    for (int k = 0; k < NSLICE; ++k) {
        const float2 pr = part[k * NPOINTS + p];
        md = fminf(md, pr.x);
        c += __float_as_int(pr.y);
    }

    float d = sqrtf(fmaxf(md, EPS));
    if (c & 1) d = -d;
    const float val = fmaxf(d + THRESHOLD, 0.0f);

    const int b = p / NPTB;
    const int a = (p % NPTB) / 30;
    atomicAdd(out + b * 10 + a, val);
}

extern "C" void kernel_launch(void* const* d_in, const int* in_sizes, int n_in,
                              void* d_out, int out_size, void* d_ws, size_t ws_size,
                              hipStream_t stream) {
    const float* points = (const float*)d_in[0];   // (16,10,30,2)
    const float* polys  = (const float*)d_in[1];   // (16,16,200,2)
    float* out = (float*)d_out;                    // (16,10)

    char* ws = (char*)d_ws;
    Seg*    table = (Seg*)ws;                      // 16*3200*32 B = 1.64 MB
    float2* part  = (float2*)(ws + (2u << 20));    // 64*4800*8 B  = 2.46 MB

    precompute_kernel<<<NB * NSEG_PAD / 256, 256, 0, stream>>>(polys, table, out);

    dim3 grid(NSLICE, NB);                         // 64 x 16 = 1024 blocks
    seg_kernel<<<grid, 320, 0, stream>>>(points, table, part);

    final_kernel<<<(NPOINTS + 255) / 256, 256, 0, stream>>>(part, out);
}